// Round 4
// baseline (365.380 us; speedup 1.0000x reference)
//
#include <hip/hip_runtime.h>
#include <cstdint>
#include <cstddef>
#include <math.h>

#define NN 100000
#define NE 1600000
#define NB ((NN + 255) / 256)   // 391 node buckets (256 nodes each)
#define EB 400                  // build blocks
#define EPB (NE / EB)           // 4000 edges per block
#define CAP 5120                // padded bucket capacity (mean 4092, sigma~64)

// GEMM tiling: 512 threads, 128 nodes/block, per-thread 4 nodes x 4 feats.
#define GT_NODES 128
#define GT_KC 32
#define GT_STRIDE 132

typedef unsigned short u16;

__device__ __forceinline__ float bf2f(u16 u) {
    union { unsigned i; float f; } c; c.i = ((unsigned)u) << 16; return c.f;
}
__device__ __forceinline__ u16 f2bf(float f) {  // round-to-nearest-even
    union { float f; unsigned int i; } c; c.f = f;
    unsigned int lsb = (c.i >> 16) & 1u;
    return (u16)((c.i + 0x7fffu + lsb) >> 16);
}
__device__ __forceinline__ unsigned int pack2(float a, float b) {
    return (unsigned int)f2bf(a) | ((unsigned int)f2bf(b) << 16);
}

__device__ __forceinline__ int load_idx(const void* ei, int isI64, int pos) {
    if (isI64) return (int)((const long long*)ei)[pos];
    return ((const int*)ei)[pos];
}

// ---------- fused CSR phase A: detect + hist + scatter into padded buckets ----
__global__ __launch_bounds__(256) void k_build(const void* __restrict__ ei,
                                               int* __restrict__ cursor,
                                               int* __restrict__ csr_tmp) {
    __shared__ int sbuf[EPB];      // 16,000 B
    __shared__ int dbuf[EPB];      // 16,000 B
    __shared__ int cnt[NB];
    __shared__ int basel[NB];
    __shared__ int anynz;

    // per-block int64/int32 detection (odd words of first 1024 entries)
    const int* p = (const int*)ei;
    if (threadIdx.x == 0) anynz = 0;
    for (int i = threadIdx.x; i < NB; i += 256) cnt[i] = 0;
    __syncthreads();
    int nz = 0;
    for (int i = threadIdx.x; i < 1024; i += 256) nz |= (p[2 * i + 1] != 0);
    if (nz) anynz = 1;   // benign race: all writers store 1
    __syncthreads();
    int isI64 = (anynz == 0);

    int base = blockIdx.x * EPB;
    for (int i = threadIdx.x; i < EPB; i += 256) {
        int s = load_idx(ei, isI64, base + i);
        int d = load_idx(ei, isI64, NE + base + i);
        sbuf[i] = s;
        dbuf[i] = d;
        atomicAdd(&cnt[d >> 8], 1);
    }
    __syncthreads();
    for (int j = threadIdx.x; j < NB; j += 256) {
        int c = cnt[j];
        int g = c ? atomicAdd(&cursor[j], c) : 0;
        basel[j] = j * CAP + g;
        cnt[j] = 0;   // reuse as local placement cursor
    }
    __syncthreads();
    for (int i = threadIdx.x; i < EPB; i += 256) {
        int s = sbuf[i];
        int d = dbuf[i];
        int bkt = d >> 8;
        int slot = basel[bkt] + atomicAdd(&cnt[bkt], 1);
        csr_tmp[slot] = ((d & 255) << 17) | s;   // dstlocal<<17 | src
    }
}

// ---------- CSR phase B: per-bucket counting sort -> csr + deg/offs/dis ------
__global__ __launch_bounds__(256) void k_sort(const int* __restrict__ cursor,
                                              const int* __restrict__ csr_tmp,
                                              int* __restrict__ csr,
                                              int* __restrict__ deg,
                                              int* __restrict__ offs,
                                              float* __restrict__ dis) {
    __shared__ int h[256];
    __shared__ int sc[256];
    __shared__ int cur[256];
    int j = blockIdx.x;
    int s0 = j * CAP, s1 = s0 + cursor[j];
    h[threadIdx.x] = 0;
    __syncthreads();
    for (int p = s0 + threadIdx.x; p < s1; p += 256)
        atomicAdd(&h[csr_tmp[p] >> 17], 1);
    __syncthreads();
    int v = h[threadIdx.x];
    sc[threadIdx.x] = v;
    __syncthreads();
#pragma unroll
    for (int off = 1; off < 256; off <<= 1) {
        int u = (threadIdx.x >= off) ? sc[threadIdx.x - off] : 0;
        __syncthreads();
        sc[threadIdx.x] += u;
        __syncthreads();
    }
    int excl = sc[threadIdx.x] - v;
    int node = j * 256 + threadIdx.x;
    if (node < NN) {
        deg[node] = v;
        offs[node] = s0 + excl;
        dis[node] = rsqrtf((float)(v + 1));  // +1 self-loop
    }
    cur[threadIdx.x] = excl;
    __syncthreads();
    for (int p = s0 + threadIdx.x; p < s1; p += 256) {
        int pk = csr_tmp[p];
        int dl = pk >> 17;
        int pos = s0 + atomicAdd(&cur[dl], 1);
        csr[pos] = pk & 0x1FFFF;   // plain src index
    }
}

// ---------- register-tiled GEMM (512 thr, 128 nodes/blk, 4x4/thread) ----------
// Used standalone only for layer 1 (K=128, global fp32 input).
template <int K, int FR, bool RELU>
__global__ __launch_bounds__(512) void k_gemm(const float* __restrict__ x,
                                              const float* __restrict__ W,
                                              const float* __restrict__ dis,
                                              u16* __restrict__ out) {
    __shared__ float xT[GT_KC * GT_STRIDE];   // 16,896 B
    __shared__ float Wc[GT_KC * 64];          //  8,192 B
    const int tid = threadIdx.x;
    const int r = tid >> 4;
    const int c = tid & 15;
    const int f4 = tid & 7;
    const int nrow = tid >> 3;
    const int nbase = blockIdx.x * GT_NODES;

    float acc[4][4];
#pragma unroll
    for (int i = 0; i < 4; ++i)
#pragma unroll
        for (int j = 0; j < 4; ++j) acc[i][j] = 0.f;

    for (int kc = 0; kc < K; kc += GT_KC) {
#pragma unroll
        for (int q = 0; q < 4; ++q) {
            int e = q * 512 + tid;
            int kk = e >> 6, j = e & 63;
            Wc[kk * 64 + j] = (j < FR) ? W[(size_t)(kc + kk) * FR + j] : 0.f;
        }
#pragma unroll
        for (int q = 0; q < 2; ++q) {
            int nl = q * 64 + nrow;
            int n = nbase + nl;
            float4 v = make_float4(0.f, 0.f, 0.f, 0.f);
            if (n < NN) v = *(const float4*)(x + (size_t)n * K + kc + f4 * 4);
            if (RELU) {
                v.x = fmaxf(v.x, 0.f); v.y = fmaxf(v.y, 0.f);
                v.z = fmaxf(v.z, 0.f); v.w = fmaxf(v.w, 0.f);
            }
            xT[(f4 * 4 + 0) * GT_STRIDE + nl] = v.x;
            xT[(f4 * 4 + 1) * GT_STRIDE + nl] = v.y;
            xT[(f4 * 4 + 2) * GT_STRIDE + nl] = v.z;
            xT[(f4 * 4 + 3) * GT_STRIDE + nl] = v.w;
        }
        __syncthreads();
#pragma unroll 8
        for (int kk = 0; kk < GT_KC; ++kk) {
            float4 a = *(const float4*)&xT[kk * GT_STRIDE + r * 4];
            float4 w = *(const float4*)&Wc[kk * 64 + c * 4];
            float xa[4] = {a.x, a.y, a.z, a.w};
            float wb[4] = {w.x, w.y, w.z, w.w};
#pragma unroll
            for (int i = 0; i < 4; ++i)
#pragma unroll
                for (int j = 0; j < 4; ++j)
                    acc[i][j] = fmaf(xa[i], wb[j], acc[i][j]);
        }
        __syncthreads();
    }
    if (c * 4 < FR) {
#pragma unroll
        for (int i = 0; i < 4; ++i) {
            int n = nbase + r * 4 + i;
            if (n < NN) {
                float dv = dis[n];
                uint2 o;
                o.x = pack2(dv * acc[i][0], dv * acc[i][1]);
                o.y = pack2(dv * acc[i][2], dv * acc[i][3]);
                *(uint2*)(out + (size_t)n * FR + c * 4) = o;
            }
        }
    }
}

// ---------- gather batch helper: B edges, SGPR row-base addressing ----------
// Indices delivered via v_readlane -> SGPR; row pointer g + s*F is wave-
// uniform so the backend forms it on the SALU pipe and each gather is
// global_load_ushort vdst, v_off(fc*2), s[base] -- ONE dest VGPR per
// outstanding load. Masked lanes gather row 0 (hot line), then zeroed.
template <int F, int B, bool MASK>
__device__ __forceinline__ float gb(int myidx, int i, int lim,
                                    const u16* __restrict__ g, unsigned fc) {
    const u16* rp[B];
#pragma unroll
    for (int k = 0; k < B; ++k) {
        int s = __builtin_amdgcn_readlane(myidx, i + k);
        rp[k] = g + (size_t)(unsigned)s * (unsigned)F;   // uniform -> SGPR base
    }
    u16 hh[B];
#pragma unroll
    for (int k = 0; k < B; ++k) hh[k] = rp[k][fc];
    float t0 = 0.f, t1 = 0.f, t2 = 0.f, t3 = 0.f;
#pragma unroll
    for (int k = 0; k < B; ++k) {
        float v = bf2f(hh[k]);
        if (MASK) v = (i + k < lim) ? v : 0.f;
        if ((k & 3) == 0) t0 += v;
        else if ((k & 3) == 1) t1 += v;
        else if ((k & 3) == 2) t2 += v;
        else t3 += v;
    }
    return (t0 + t1) + (t2 + t3);
}

// per-node row aggregation (R13 proven form), F = source row width
template <int F>
__device__ __forceinline__ float grow(int n, unsigned fc,
                                      const int* __restrict__ offs,
                                      const int* __restrict__ deg,
                                      const int* __restrict__ csr,
                                      const u16* __restrict__ g) {
    int start = __builtin_amdgcn_readfirstlane(offs[n]);
    int len   = __builtin_amdgcn_readfirstlane(deg[n]);
    unsigned f = fc;  // caller guarantees fc < 64 lane mapping
    float acc = bf2f(g[(unsigned)n * F + fc]);  // self-loop (pre-scaled)

    int myidx = 0;
    if ((int)f < len) myidx = csr[start + (int)f];
    int lim = (len < 64) ? len : 64;

    if (lim > 0) {
        if (lim >= 33) {
            int i = 0;
            for (; i + 16 <= lim; i += 16)
                acc += gb<F, 16, false>(myidx, i, lim, g, fc);
            if (i < lim)
                acc += gb<F, 16, true>(myidx, i, lim, g, fc);
        } else if (lim >= 17) {
            acc += gb<F, 32, true>(myidx, 0, lim, g, fc);
        } else if (lim == 16) {
            acc += gb<F, 16, false>(myidx, 0, lim, g, fc);
        } else {
            acc += gb<F, 16, true>(myidx, 0, lim, g, fc);
        }
    }
    // rare fallback: deg > 64 (essentially never for Poisson(16))
    if (len > 64) {
        int ii = 64;
        for (; ii + 2 <= len; ii += 2) {
            int s0 = __builtin_amdgcn_readfirstlane(csr[start + ii + 0]);
            int s1 = __builtin_amdgcn_readfirstlane(csr[start + ii + 1]);
            u16 h0 = g[(unsigned)s0 * F + fc];
            u16 h1 = g[(unsigned)s1 * F + fc];
            acc += bf2f(h0) + bf2f(h1);
        }
        if (ii < len) {
            int s0 = __builtin_amdgcn_readfirstlane(csr[start + ii]);
            acc += bf2f(g[(unsigned)s0 * F + fc]);
        }
    }
    return acc;
}

// ---------- R14: fused gather+GEMM (layers 2,3) ----------
// Block owns 128 nodes. Phase 1: 8 waves gather 16 nodes each from gin
// (64-wide bf16, pre-scaled by dis[src]), apply dis[dst]*acc + bprev, ReLU,
// store fp32 feature-major into LDS actT[64][132]. Phase 2: register-tiled
// GEMM actT @ Wc (Wc zero-padded to 64 cols), epilogue scales by dis[n],
// packs bf16 rows into gout. Deletes the global act round-trip entirely;
// resident blocks desync so GEMM VALU work hides under the gather wall.
template <int FR>
__global__ __launch_bounds__(512) void k_fuse(const int* __restrict__ offs,
                                              const int* __restrict__ deg,
                                              const int* __restrict__ csr,
                                              const float* __restrict__ dis,
                                              const u16* __restrict__ gin,
                                              const float* __restrict__ bprev,
                                              const float* __restrict__ W,
                                              u16* __restrict__ gout) {
    __shared__ float actT[64 * GT_STRIDE];   // 33,792 B  (feature-major)
    __shared__ float Wc[64 * 64];            // 16,384 B  (zero-padded cols>=FR)
    const int tid = threadIdx.x;
    const int nbase = blockIdx.x * GT_NODES;

    for (int e = tid; e < 64 * 64; e += 512) {
        int kk = e >> 6, j = e & 63;
        Wc[e] = (j < FR) ? W[(size_t)kk * FR + j] : 0.f;
    }

    // ---- phase 1: gather 128 node rows into actT ----
    const int w = tid >> 6;
    const unsigned f = tid & 63;
    for (int t = 0; t < 16; ++t) {
        int nl = w * 16 + t;
        int n = nbase + nl;
        float v = 0.f;
        if (n < NN) {
            float acc = grow<64>(n, f, offs, deg, csr, gin);
            v = fmaxf(dis[n] * acc + bprev[f], 0.f);   // conv bias + ReLU
        }
        actT[f * GT_STRIDE + nl] = v;
    }
    __syncthreads();

    // ---- phase 2: GEMM actT(128x64) @ W(64xFR) ----
    const int r = tid >> 4;
    const int c = tid & 15;
    float acc[4][4];
#pragma unroll
    for (int i = 0; i < 4; ++i)
#pragma unroll
        for (int j = 0; j < 4; ++j) acc[i][j] = 0.f;
#pragma unroll 8
    for (int kk = 0; kk < 64; ++kk) {
        float4 a = *(const float4*)&actT[kk * GT_STRIDE + r * 4];
        float4 wv = *(const float4*)&Wc[kk * 64 + c * 4];
        float xa[4] = {a.x, a.y, a.z, a.w};
        float wb[4] = {wv.x, wv.y, wv.z, wv.w};
#pragma unroll
        for (int i = 0; i < 4; ++i)
#pragma unroll
            for (int j = 0; j < 4; ++j)
                acc[i][j] = fmaf(xa[i], wb[j], acc[i][j]);
    }
    if (c * 4 < FR) {
#pragma unroll
        for (int i = 0; i < 4; ++i) {
            int n = nbase + r * 4 + i;
            if (n < NN) {
                float dv = dis[n];
                uint2 o;
                o.x = pack2(dv * acc[i][0], dv * acc[i][1]);
                o.y = pack2(dv * acc[i][2], dv * acc[i][3]);
                *(uint2*)(gout + (size_t)n * FR + c * 4) = o;
            }
        }
    }
}

// ---------- final gather (layer-3 aggregation + bias + log_softmax) ----------
template <int F, bool SOFTMAX>
__global__ __launch_bounds__(256) void k_gather(const int* __restrict__ offs,
                                                const int* __restrict__ deg,
                                                const int* __restrict__ csr,
                                                const float* __restrict__ dis,
                                                const u16* __restrict__ g,
                                                const float* __restrict__ b,
                                                float* __restrict__ out) {
    int n = blockIdx.x * 4 + (threadIdx.x >> 6);
    unsigned f = threadIdx.x & 63;
    if (n >= NN) return;
    unsigned fc = (f < (unsigned)F) ? f : 0u;
    float dvn = dis[n];
    float bf  = b[fc];
    float acc = grow<F>(n, fc, offs, deg, csr, g);
    float v = dvn * acc + bf;
    if (!SOFTMAX) {
        if (f < (unsigned)F) out[(size_t)n * F + f] = v;
    } else {
        float vv = (f < (unsigned)F) ? v : -INFINITY;
        float m = vv;
#pragma unroll
        for (int off = 32; off; off >>= 1) m = fmaxf(m, __shfl_xor(m, off));
        float ex = (f < (unsigned)F) ? __expf(vv - m) : 0.f;
        float sum = ex;
#pragma unroll
        for (int off = 32; off; off >>= 1) sum += __shfl_xor(sum, off);
        if (f < (unsigned)F) out[(size_t)n * F + f] = vv - m - logf(sum);
    }
}

extern "C" void kernel_launch(void* const* d_in, const int* in_sizes, int n_in,
                              void* d_out, int out_size, void* d_ws, size_t ws_size,
                              hipStream_t stream) {
    const float* x  = (const float*)d_in[0];
    const void*  ei = d_in[1];
    const float* W1 = (const float*)d_in[2];
    const float* b1 = (const float*)d_in[3];
    const float* W2 = (const float*)d_in[4];
    const float* b2 = (const float*)d_in[5];
    const float* W3 = (const float*)d_in[6];
    const float* b3 = (const float*)d_in[7];
    float* out = (float*)d_out;

    char* ws = (char*)d_ws;
    size_t off = 0;
    auto alloc = [&](size_t bytes) { void* p = ws + off; off += (bytes + 255) & ~255ULL; return p; };
    int*   cursor  = (int*)alloc(NB * 4);
    int*   deg     = (int*)alloc(NN * 4);
    float* dis     = (float*)alloc(NN * 4);
    int*   offs    = (int*)alloc(NN * 4);
    int*   csr_tmp = (int*)alloc((size_t)NB * CAP * 4);   // 8 MB padded
    int*   csr     = (int*)alloc((size_t)NB * CAP * 4);   // 8 MB padded
    u16*   gbuf    = (u16*)alloc((size_t)NN * 64 * 2);    // bf16 staging (12.8 MB)
    u16*   gbuf2   = (u16*)alloc((size_t)NN * 64 * 2);    // second staging buffer

    // CSR build: 2 kernels (padded-bucket counting sort, no global prefix)
    hipMemsetAsync(cursor, 0, NB * 4, stream);
    k_build<<<EB, 256, 0, stream>>>(ei, cursor, csr_tmp);
    k_sort<<<NB, 256, 0, stream>>>(cursor, csr_tmp, csr, deg, offs, dis);

    const int gemm_grid = (NN + GT_NODES - 1) / GT_NODES;   // 782
    const int gather_grid = (NN + 3) / 4;

    // layer 1 GEMM: gbuf = bf16(dis * (x @ W1))
    k_gemm<128, 64, false><<<gemm_grid, 512, 0, stream>>>(x, W1, dis, gbuf);

    // fused: act1 = relu(dis*sum(gbuf)+b1);  gbuf2 = bf16(dis*(act1@W2))
    k_fuse<64><<<gemm_grid, 512, 0, stream>>>(offs, deg, csr, dis, gbuf, b1, W2, gbuf2);

    // fused: act2 = relu(dis*sum(gbuf2)+b2); gbuf = bf16(dis*(act2@W3)) (40-wide)
    k_fuse<40><<<gemm_grid, 512, 0, stream>>>(offs, deg, csr, dis, gbuf2, b2, W3, gbuf);

    // final: out = log_softmax(dis*sum(gbuf) + b3)
    k_gather<40, true><<<gather_grid, 256, 0, stream>>>(offs, deg, csr, dis, gbuf, b3, out);
}